// Round 14
// baseline (55.056 us; speedup 1.0000x reference)
//
#include <hip/hip_runtime.h>
#include <hip/hip_bf16.h>
#include <stdint.h>

// QuantizedLinear: out[m][n] = (sum_k x[m][k]*W[n][k]) * scale + bias[n]
// M=256, K=4096, N=11008. W int8-valued -> exact in bf16; scale/bias f32 epilogue.
//
// R14 = R12 exactly (best measured: 51.5us) + nontemporal OUT stores.
// R12 recap: W requested exactly once (256 blocks = 1/CU, tile 256m x 43n,
// 11008 = 256*43); 512 thr = 8 waves; BK=128, NT=32; W global->reg ring-4 ->
// write-side cvt -> 4-slot bf16 LDS ring (272B pitch); A packed-frag ping-pong
// (cvt_x pre-pass, L2-resident); setprio around MFMA; vmcnt never drained;
// pair-fused barriers (one lgkmcnt(0)+s_barrier per 2 iters).
// R14 change: out is written once and never read -- nontemporal stores keep
// the 11MB/replay from evicting W in L3 (replay FETCH ~96MB => W half-L3-
// resident; every extra resident MB is HBM traffic saved next replay).
// R13's compute-first reorder REGRESSED (53.4) -> reverted.

#define MM 256
#define NN 11008
#define KK 4096
#define BK 128
#define NT (KK / BK)        // 32
#define NSW 43              // n-cols per block (11008 = 256*43), staged EXACTLY
#define ROWB 272            // bf16 row pitch bytes (256 data + 16 pad)
#define SLOTB (NSW * ROWB)  // 11696 B per LDS slot
#define NSLOT 4             // 46784 B LDS total

typedef __bf16 bf16x8 __attribute__((ext_vector_type(8)));
typedef float  f32x4  __attribute__((ext_vector_type(4)));

// ---- pass 1: x f32 [256][4096] -> bf16 packed in MFMA A-fragment order ----
// xf[(mb*128 + kb)*64 + l] = bf16x8 { x[mb*16 + (l&15)][kb*32 + (l>>4)*8 + j] }
__global__ void cvt_x_kernel(const float* __restrict__ x, bf16x8* __restrict__ xf) {
    int i  = blockIdx.x * 256 + threadIdx.x;   // 0..131071
    int l  = i & 63;
    int kb = (i >> 6) & 127;
    int mb = i >> 13;
    int m  = mb * 16 + (l & 15);
    int k  = kb * 32 + (l >> 4) * 8;
    const float* p = x + (size_t)m * KK + k;
    float4 v0 = *(const float4*)p;
    float4 v1 = *(const float4*)(p + 4);
    union { __bf16 b[8]; bf16x8 v; } t;
    t.b[0] = (__bf16)v0.x; t.b[1] = (__bf16)v0.y;
    t.b[2] = (__bf16)v0.z; t.b[3] = (__bf16)v0.w;
    t.b[4] = (__bf16)v1.x; t.b[5] = (__bf16)v1.y;
    t.b[6] = (__bf16)v1.z; t.b[7] = (__bf16)v1.w;
    xf[i] = t.v;
}

// ---- pass 2: GEMM. 512 thr = 8 waves; wave w owns m-rows [w*32, +32) x 43 n ----
__global__ __launch_bounds__(512, 2) void qlin_gemm(
    const bf16x8* __restrict__ xf, const int* __restrict__ wq,
    const float* __restrict__ scale, const float* __restrict__ bias,
    float* __restrict__ out) {

    __shared__ __align__(16) char wsm[NSLOT * SLOTB];   // 46784 B

    const int tid  = threadIdx.x;
    const int lane = tid & 63;
    const int wid  = tid >> 6;          // 0..7
    const int nl   = lane & 15;
    const int qh   = lane >> 4;

    const int n0 = blockIdx.x * NSW;    // 0..10965; last block row = 11007 exactly

    // --- W staging: threads 0..343; thread -> tile-row sr = tid>>3 (0..42),
    //     k-slot sl = tid&7 (16 ints = 4 int4 = 64B -> 32B bf16). No clamps.
    const bool stager = (tid < NSW * 8);
    const int sr = tid >> 3;
    const int sl = tid & 7;
    const int* wsrc = wq + (size_t)(n0 + sr) * KK + sl * 16;
    const int wdst  = sr * ROWB + sl * 32;

    // --- B fragment read rows (clamped for pad cols; those cols masked at store) ---
    int brd[3];
#pragma unroll
    for (int fn = 0; fn < 3; ++fn) {
        int r = fn * 16 + nl; if (r > NSW - 1) r = NSW - 1;
        brd[fn] = r * ROWB + qh * 16;
    }

    // --- A fragments (packed, L2/L3-resident): mb = wid*2 + fmr ---
    const bf16x8* abase = xf + ((size_t)(wid * 2) * 128) * 64 + lane;

    f32x4 acc[2][3] = {};
    int4   R0[4], R1[4], R2[4], R3[4];   // W reg ring: tile u in slot u&3
    bf16x8 AA[8], AB[8];                 // A ping-pong: tile u in buf u&1; [fmr*4+kb]

    auto loadW = [&](int4 (&r)[4], int t) {
        if (stager) {
            const int* p = wsrc + t * BK;
#pragma unroll
            for (int j = 0; j < 4; ++j)
                r[j] = *(const int4*)(p + j * 4);
        }
    };
    auto loadA = [&](bf16x8 (&A)[8], int t) {
#pragma unroll
        for (int fmr = 0; fmr < 2; ++fmr)
#pragma unroll
            for (int kb = 0; kb < 4; ++kb)
                A[fmr * 4 + kb] = abase[((size_t)fmr * 128 + t * 4 + kb) * 64];
    };
    auto writeW = [&](const int4 (&r)[4], int slotoff) {
        if (stager) {
            union { __bf16 e[16]; bf16x8 v[2]; } c;
#pragma unroll
            for (int j = 0; j < 4; ++j) {
                c.e[j * 4 + 0] = (__bf16)(float)r[j].x;
                c.e[j * 4 + 1] = (__bf16)(float)r[j].y;
                c.e[j * 4 + 2] = (__bf16)(float)r[j].z;
                c.e[j * 4 + 3] = (__bf16)(float)r[j].w;
            }
            char* d = wsm + slotoff + wdst;
            *(bf16x8*)d = c.v[0];
            *(bf16x8*)(d + 16) = c.v[1];
        }
    };
    auto compute = [&](const bf16x8 (&A)[8], int slotoff) {
        const char* B = wsm + slotoff;
        __builtin_amdgcn_s_setprio(1);
#pragma unroll
        for (int ks = 0; ks < 4; ++ks) {
            bf16x8 b[3];
#pragma unroll
            for (int fn = 0; fn < 3; ++fn)
                b[fn] = *(const bf16x8*)(B + brd[fn] + ks * 64);
#pragma unroll
            for (int fmr = 0; fmr < 2; ++fmr)
#pragma unroll
                for (int fn = 0; fn < 3; ++fn)
                    acc[fmr][fn] = __builtin_amdgcn_mfma_f32_16x16x32_bf16(
                        A[fmr * 4 + ks], b[fn], acc[fmr][fn], 0, 0, 0);
        }
        __builtin_amdgcn_s_setprio(0);
    };

    // ---- prologue: W(0..3) -> reg ring; A(0),A(1); tiles 0,1 -> LDS slots 0,1 ----
    loadW(R0, 0); loadW(R1, 1); loadW(R2, 2); loadW(R3, 3);
    loadA(AA, 0); loadA(AB, 1);
    writeW(R0, 0 * SLOTB);
    writeW(R1, 1 * SLOTB);
    asm volatile("s_waitcnt lgkmcnt(0)" ::: "memory");
    __builtin_amdgcn_s_barrier();

    // ---- iter t: loadW(W(t+4)); writeW(tile t+2 -> slot (t+2)&3);
    //              compute(t, slot t&3); loadA(t+2 into just-freed buf).
    //      Sync only at pair boundaries (every 2 iters). ----
#define STEP_A(T, WL, WS, AC)                                        \
    {                                                                \
        const int t_ = (T);                                          \
        loadW(WL, (t_ + 4 < NT) ? t_ + 4 : NT - 1);                  \
        writeW(WS, ((t_ + 2) & 3) * SLOTB);                          \
        compute(AC, (t_ & 3) * SLOTB);                               \
        loadA(AC, (t_ + 2 < NT) ? t_ + 2 : NT - 1);                  \
    }
#define STEP_B(T, WL, WS, AC)                                        \
    {                                                                \
        STEP_A(T, WL, WS, AC)                                        \
        asm volatile("s_waitcnt lgkmcnt(0)" ::: "memory");           \
        __builtin_amdgcn_s_barrier();                                \
    }

#pragma unroll 1
    for (int tq = 0; tq < NT / 4; ++tq) {
        const int t0 = tq * 4;
        STEP_A(t0 + 0, R0, R2, AA)   // reload R0 <- W(t+4); publish tile t+2 (R2)
        STEP_B(t0 + 1, R1, R3, AB)
        STEP_A(t0 + 2, R2, R0, AA)
        STEP_B(t0 + 3, R3, R1, AB)
    }
#undef STEP_A
#undef STEP_B

    // ---- epilogue: D layout col=nl, row=qh*4+r; mask pad cols; y=acc*sc+bias.
    //      Nontemporal stores: out is write-once/read-never; keep it out of L3
    //      so W stays resident across timed replays. ----
    const float sc = scale[0];
#pragma unroll
    for (int fn = 0; fn < 3; ++fn) {
        const int ncol = fn * 16 + nl;
        if (ncol < NSW) {
            const int n = n0 + ncol;
            const float bv = bias[n];
#pragma unroll
            for (int fmr = 0; fmr < 2; ++fmr) {
                const int m = wid * 32 + fmr * 16 + qh * 4;
#pragma unroll
                for (int r = 0; r < 4; ++r)
                    __builtin_nontemporal_store(acc[fmr][fn][r] * sc + bv,
                                                &out[(size_t)(m + r) * NN + n]);
            }
        }
    }
}

extern "C" void kernel_launch(void* const* d_in, const int* in_sizes, int n_in,
                              void* d_out, int out_size, void* d_ws, size_t ws_size,
                              hipStream_t stream) {
    const float* x     = (const float*)d_in[0];
    const int*   wq    = (const int*)d_in[1];
    const float* scale = (const float*)d_in[2];
    const float* bias  = (const float*)d_in[3];
    float* out = (float*)d_out;
    bf16x8* xf = (bf16x8*)d_ws;   // 2 MB packed-A scratch

    cvt_x_kernel<<<dim3(MM * KK / (256 * 8)), dim3(256), 0, stream>>>(x, xf);
    qlin_gemm<<<dim3(NN / NSW), dim3(512), 0, stream>>>(xf, wq, scale, bias, out);
}

// Round 15
// 51.565 us; speedup vs baseline: 1.0677x; 1.0677x over previous
//
#include <hip/hip_runtime.h>
#include <hip/hip_bf16.h>
#include <stdint.h>

// QuantizedLinear: out[m][n] = (sum_k x[m][k]*W[n][k]) * scale + bias[n]
// M=256, K=4096, N=11008. W int8-valued -> exact in bf16; scale/bias f32 epilogue.
//
// R15 = R12 exact revert (best measured: 51.5us; R13 reorder and R14
// nontemporal stores both regressed) + ONE change inside compute():
// all 12 B-fragment ds_read_b128s are issued BEFORE the 24 MFMAs (explicit
// preload -> first MFMA waits only on the first reads; the other 9 complete
// under MFMA issue). With only 2 waves/SIMD (pinned by the W-once geometry:
// 256 blocks = 1/CU), per-wave ILP is the only latency-hiding left.
// R12 recap: W requested exactly once (tile 256m x 43n, 11008 = 256*43);
// 512 thr = 8 waves; BK=128, NT=32; W global->reg ring-4 -> write-side cvt ->
// 4-slot bf16 LDS ring (272B pitch, 2-way banks free); A packed-frag
// ping-pong (cvt_x pre-pass, L2-resident); setprio around MFMA; vmcnt never
// drained; pair-fused barriers (one lgkmcnt(0)+s_barrier per 2 iters).

#define MM 256
#define NN 11008
#define KK 4096
#define BK 128
#define NT (KK / BK)        // 32
#define NSW 43              // n-cols per block (11008 = 256*43), staged EXACTLY
#define ROWB 272            // bf16 row pitch bytes (256 data + 16 pad)
#define SLOTB (NSW * ROWB)  // 11696 B per LDS slot
#define NSLOT 4             // 46784 B LDS total

typedef __bf16 bf16x8 __attribute__((ext_vector_type(8)));
typedef float  f32x4  __attribute__((ext_vector_type(4)));

// ---- pass 1: x f32 [256][4096] -> bf16 packed in MFMA A-fragment order ----
// xf[(mb*128 + kb)*64 + l] = bf16x8 { x[mb*16 + (l&15)][kb*32 + (l>>4)*8 + j] }
__global__ void cvt_x_kernel(const float* __restrict__ x, bf16x8* __restrict__ xf) {
    int i  = blockIdx.x * 256 + threadIdx.x;   // 0..131071
    int l  = i & 63;
    int kb = (i >> 6) & 127;
    int mb = i >> 13;
    int m  = mb * 16 + (l & 15);
    int k  = kb * 32 + (l >> 4) * 8;
    const float* p = x + (size_t)m * KK + k;
    float4 v0 = *(const float4*)p;
    float4 v1 = *(const float4*)(p + 4);
    union { __bf16 b[8]; bf16x8 v; } t;
    t.b[0] = (__bf16)v0.x; t.b[1] = (__bf16)v0.y;
    t.b[2] = (__bf16)v0.z; t.b[3] = (__bf16)v0.w;
    t.b[4] = (__bf16)v1.x; t.b[5] = (__bf16)v1.y;
    t.b[6] = (__bf16)v1.z; t.b[7] = (__bf16)v1.w;
    xf[i] = t.v;
}

// ---- pass 2: GEMM. 512 thr = 8 waves; wave w owns m-rows [w*32, +32) x 43 n ----
__global__ __launch_bounds__(512, 2) void qlin_gemm(
    const bf16x8* __restrict__ xf, const int* __restrict__ wq,
    const float* __restrict__ scale, const float* __restrict__ bias,
    float* __restrict__ out) {

    __shared__ __align__(16) char wsm[NSLOT * SLOTB];   // 46784 B

    const int tid  = threadIdx.x;
    const int lane = tid & 63;
    const int wid  = tid >> 6;          // 0..7
    const int nl   = lane & 15;
    const int qh   = lane >> 4;

    const int n0 = blockIdx.x * NSW;    // 0..10965; last block row = 11007 exactly

    // --- W staging: threads 0..343; thread -> tile-row sr = tid>>3 (0..42),
    //     k-slot sl = tid&7 (16 ints = 4 int4 = 64B -> 32B bf16). No clamps.
    const bool stager = (tid < NSW * 8);
    const int sr = tid >> 3;
    const int sl = tid & 7;
    const int* wsrc = wq + (size_t)(n0 + sr) * KK + sl * 16;
    const int wdst  = sr * ROWB + sl * 32;

    // --- B fragment read rows (clamped for pad cols; those cols masked at store) ---
    int brd[3];
#pragma unroll
    for (int fn = 0; fn < 3; ++fn) {
        int r = fn * 16 + nl; if (r > NSW - 1) r = NSW - 1;
        brd[fn] = r * ROWB + qh * 16;
    }

    // --- A fragments (packed, L2/L3-resident): mb = wid*2 + fmr ---
    const bf16x8* abase = xf + ((size_t)(wid * 2) * 128) * 64 + lane;

    f32x4 acc[2][3] = {};
    int4   R0[4], R1[4], R2[4], R3[4];   // W reg ring: tile u in slot u&3
    bf16x8 AA[8], AB[8];                 // A ping-pong: tile u in buf u&1; [fmr*4+kb]

    auto loadW = [&](int4 (&r)[4], int t) {
        if (stager) {
            const int* p = wsrc + t * BK;
#pragma unroll
            for (int j = 0; j < 4; ++j)
                r[j] = *(const int4*)(p + j * 4);
        }
    };
    auto loadA = [&](bf16x8 (&A)[8], int t) {
#pragma unroll
        for (int fmr = 0; fmr < 2; ++fmr)
#pragma unroll
            for (int kb = 0; kb < 4; ++kb)
                A[fmr * 4 + kb] = abase[((size_t)fmr * 128 + t * 4 + kb) * 64];
    };
    auto writeW = [&](const int4 (&r)[4], int slotoff) {
        if (stager) {
            union { __bf16 e[16]; bf16x8 v[2]; } c;
#pragma unroll
            for (int j = 0; j < 4; ++j) {
                c.e[j * 4 + 0] = (__bf16)(float)r[j].x;
                c.e[j * 4 + 1] = (__bf16)(float)r[j].y;
                c.e[j * 4 + 2] = (__bf16)(float)r[j].z;
                c.e[j * 4 + 3] = (__bf16)(float)r[j].w;
            }
            char* d = wsm + slotoff + wdst;
            *(bf16x8*)d = c.v[0];
            *(bf16x8*)(d + 16) = c.v[1];
        }
    };
    auto compute = [&](const bf16x8 (&A)[8], int slotoff) {
        const char* B = wsm + slotoff;
        __builtin_amdgcn_s_setprio(1);
        // explicit preload: all 12 B-frag reads issued before any MFMA
        bf16x8 b[4][3];
#pragma unroll
        for (int ks = 0; ks < 4; ++ks)
#pragma unroll
            for (int fn = 0; fn < 3; ++fn)
                b[ks][fn] = *(const bf16x8*)(B + brd[fn] + ks * 64);
#pragma unroll
        for (int ks = 0; ks < 4; ++ks)
#pragma unroll
            for (int fmr = 0; fmr < 2; ++fmr)
#pragma unroll
                for (int fn = 0; fn < 3; ++fn)
                    acc[fmr][fn] = __builtin_amdgcn_mfma_f32_16x16x32_bf16(
                        A[fmr * 4 + ks], b[ks][fn], acc[fmr][fn], 0, 0, 0);
        __builtin_amdgcn_s_setprio(0);
    };

    // ---- prologue: W(0..3) -> reg ring; A(0),A(1); tiles 0,1 -> LDS slots 0,1 ----
    loadW(R0, 0); loadW(R1, 1); loadW(R2, 2); loadW(R3, 3);
    loadA(AA, 0); loadA(AB, 1);
    writeW(R0, 0 * SLOTB);
    writeW(R1, 1 * SLOTB);
    asm volatile("s_waitcnt lgkmcnt(0)" ::: "memory");
    __builtin_amdgcn_s_barrier();

    // ---- iter t: loadW(W(t+4)); writeW(tile t+2 -> slot (t+2)&3);
    //              compute(t, slot t&3); loadA(t+2 into just-freed buf).
    //      Sync only at pair boundaries (every 2 iters). ----
#define STEP_A(T, WL, WS, AC)                                        \
    {                                                                \
        const int t_ = (T);                                          \
        loadW(WL, (t_ + 4 < NT) ? t_ + 4 : NT - 1);                  \
        writeW(WS, ((t_ + 2) & 3) * SLOTB);                          \
        compute(AC, (t_ & 3) * SLOTB);                               \
        loadA(AC, (t_ + 2 < NT) ? t_ + 2 : NT - 1);                  \
    }
#define STEP_B(T, WL, WS, AC)                                        \
    {                                                                \
        STEP_A(T, WL, WS, AC)                                        \
        asm volatile("s_waitcnt lgkmcnt(0)" ::: "memory");           \
        __builtin_amdgcn_s_barrier();                                \
    }

#pragma unroll 1
    for (int tq = 0; tq < NT / 4; ++tq) {
        const int t0 = tq * 4;
        STEP_A(t0 + 0, R0, R2, AA)   // reload R0 <- W(t+4); publish tile t+2 (R2)
        STEP_B(t0 + 1, R1, R3, AB)
        STEP_A(t0 + 2, R2, R0, AA)
        STEP_B(t0 + 3, R3, R1, AB)
    }
#undef STEP_A
#undef STEP_B

    // ---- epilogue: D layout col=nl, row=qh*4+r; mask pad cols; y=acc*sc+bias ----
    const float sc = scale[0];
#pragma unroll
    for (int fn = 0; fn < 3; ++fn) {
        const int ncol = fn * 16 + nl;
        if (ncol < NSW) {
            const int n = n0 + ncol;
            const float bv = bias[n];
#pragma unroll
            for (int fmr = 0; fmr < 2; ++fmr) {
                const int m = wid * 32 + fmr * 16 + qh * 4;
#pragma unroll
                for (int r = 0; r < 4; ++r)
                    out[(size_t)(m + r) * NN + n] = acc[fmr][fn][r] * sc + bv;
            }
        }
    }
}

extern "C" void kernel_launch(void* const* d_in, const int* in_sizes, int n_in,
                              void* d_out, int out_size, void* d_ws, size_t ws_size,
                              hipStream_t stream) {
    const float* x     = (const float*)d_in[0];
    const int*   wq    = (const int*)d_in[1];
    const float* scale = (const float*)d_in[2];
    const float* bias  = (const float*)d_in[3];
    float* out = (float*)d_out;
    bf16x8* xf = (bf16x8*)d_ws;   // 2 MB packed-A scratch

    cvt_x_kernel<<<dim3(MM * KK / (256 * 8)), dim3(256), 0, stream>>>(x, xf);
    qlin_gemm<<<dim3(NN / NSW), dim3(512), 0, stream>>>(xf, wq, scale, bias, out);
}